// Round 3
// baseline (434.898 us; speedup 1.0000x reference)
//
#include <hip/hip_runtime.h>

// FrequencyShiftLayer: ifft2(fft2(x) * temp) with SCALAR temp == temp * x.
// Pure elementwise complex rotation by angle Lz*dphi = 0.05 rad.
// Memory-bound streaming kernel: 512 MiB total traffic -> ~85us at 6.3 TB/s.

#define NELEM (32 * 1024 * 1024)   // B*M*N = 32*1024*1024

__global__ void __launch_bounds__(256)
freq_shift_kernel(const float4* __restrict__ xr,
                  const float4* __restrict__ xi,
                  float4* __restrict__ yr,
                  float4* __restrict__ yi,
                  int n4) {
    // cos(0.05), sin(0.05) to float32 precision
    const float c = 0.99875026039496625f;
    const float s = 0.04997916927067833f;

    int stride = gridDim.x * blockDim.x;
    for (int i = blockIdx.x * blockDim.x + threadIdx.x; i < n4; i += stride) {
        float4 r  = xr[i];
        float4 im = xi[i];
        float4 orl, oim;
        orl.x = fmaf(c, r.x, -s * im.x);
        orl.y = fmaf(c, r.y, -s * im.y);
        orl.z = fmaf(c, r.z, -s * im.z);
        orl.w = fmaf(c, r.w, -s * im.w);
        oim.x = fmaf(s, r.x,  c * im.x);
        oim.y = fmaf(s, r.y,  c * im.y);
        oim.z = fmaf(s, r.z,  c * im.z);
        oim.w = fmaf(s, r.w,  c * im.w);
        yr[i] = orl;
        yi[i] = oim;
    }
}

extern "C" void kernel_launch(void* const* d_in, const int* in_sizes, int n_in,
                              void* d_out, int out_size, void* d_ws, size_t ws_size,
                              hipStream_t stream) {
    const float4* xr = (const float4*)d_in[0];   // x_real [B,M,N] f32
    const float4* xi = (const float4*)d_in[1];   // x_imag [B,M,N] f32
    float* out = (float*)d_out;                  // [2,B,M,N] f32: real plane then imag plane
    float4* yr = (float4*)out;
    float4* yi = (float4*)(out + (size_t)NELEM);

    int n4 = NELEM / 4;                          // 8,388,608 float4 elements per tensor
    dim3 block(256);
    dim3 grid(2048);                             // grid-stride; ~16 iters/thread
    freq_shift_kernel<<<grid, block, 0, stream>>>(xr, xi, yr, yi, n4);
}